// Round 2
// baseline (458.003 us; speedup 1.0000x reference)
//
#include <hip/hip_runtime.h>

// ComplexScaling: separable bilinear resample, NHWC [N,H,W,2] fp32.
// out[n,i,j,c] = wy0*(wx0*in[n,y0,x0,c] + wx1*in[n,y0,x1,c])
//              + wy1*(wx0*in[n,y1,x0,c] + wx1*in[n,y1,x1,c])
// with zeros-padding masks folded into the wx/wy weights.
//
// Key structural fact: for s == 1.0f and power-of-two H,W the coordinate
// chain ((s*((2j+1)/W - 1) + 1)*W - 1)/2 is EXACT in fp32 (every
// intermediate is a dyadic rational representable in 24 bits), so
// ix == j, iy == i, wx1 == wy1 == 0 and the op is bitwise out = in.
// That case gets a dedicated copy path at HBM-copy speed. The general
// bilinear path (arbitrary theta) is kept below it, restructured on a
// 3D grid (no 64-bit integer divides).

// clang-native vector type: __builtin_nontemporal_* requires a real
// vector type, not HIP's HIP_vector_type<float,4> class.
typedef float f32x4 __attribute__((ext_vector_type(4)));

__global__ __launch_bounds__(256) void ComplexScaling_kernel(
    const float* __restrict__ in, const float* __restrict__ theta,
    float* __restrict__ out, int H, int W) {
  const float s = 1.0f + theta[0];

  const int i = blockIdx.y;                          // output row
  const int n = blockIdx.z;                          // batch
  const int j = (blockIdx.x * blockDim.x + threadIdx.x) << 2;  // 4 px/thread
  if (j >= W) return;

  const long long row_elems = (long long)(n * H + i) * W;      // pixels
  // element offset of this thread's 4 pixels (2 floats each)
  const long long off = (row_elems + j) * 2;                   // floats

  // ---------- fast path: identity mapping -> pure copy ----------
  // Grid-uniform branch (s is uniform), no divergence.
  if (s == 1.0f) {
    const f32x4* __restrict__ src = (const f32x4*)(in + off);
    f32x4* __restrict__ dst = (f32x4*)(out + off);
    f32x4 v0 = __builtin_nontemporal_load(src);
    f32x4 v1 = __builtin_nontemporal_load(src + 1);
    __builtin_nontemporal_store(v0, dst);
    __builtin_nontemporal_store(v1, dst + 1);
    return;
  }

  // ---------- general path: separable bilinear gather ----------
  // row (y) coordinate: shared by all 4 pixels of this thread
  float yn  = (2.0f * (float)i + 1.0f) / (float)H - 1.0f;
  float iy  = ((s * yn + 1.0f) * (float)H - 1.0f) * 0.5f;
  float fy0 = floorf(iy);
  float wy1 = iy - fy0;
  float wy0 = 1.0f - wy1;
  float fy1 = fy0 + 1.0f;
  float Hm1 = (float)(H - 1);
  if (!(fy0 >= 0.0f && fy0 <= Hm1)) wy0 = 0.0f;   // zeros padding
  if (!(fy1 >= 0.0f && fy1 <= Hm1)) wy1 = 0.0f;
  int y0 = (int)fminf(fmaxf(fy0, 0.0f), Hm1);
  int y1 = (int)fminf(fmaxf(fy1, 0.0f), Hm1);

  const float* __restrict__ row0 = in + ((long long)(n * H + y0) * W) * 2;
  const float* __restrict__ row1 = in + ((long long)(n * H + y1) * W) * 2;
  const bool need_y1 = (wy1 != 0.0f);

  float Wm1 = (float)(W - 1);
  float vx[4], vy[4];

  #pragma unroll
  for (int p = 0; p < 4; ++p) {
    int jj = j + p;
    // column (x) coordinate
    float xn  = (2.0f * (float)jj + 1.0f) / (float)W - 1.0f;
    float ix  = ((s * xn + 1.0f) * (float)W - 1.0f) * 0.5f;
    float fx0 = floorf(ix);
    float wx1 = ix - fx0;
    float wx0 = 1.0f - wx1;
    float fx1 = fx0 + 1.0f;
    if (!(fx0 >= 0.0f && fx0 <= Wm1)) wx0 = 0.0f;  // zeros padding
    if (!(fx1 >= 0.0f && fx1 <= Wm1)) wx1 = 0.0f;
    int x0 = (int)fminf(fmaxf(fx0, 0.0f), Wm1);
    int x1 = (int)fminf(fmaxf(fx1, 0.0f), Wm1);

    // top row: skip zero-weight corner loads (saves BW near-identity)
    float ax = 0.0f, ay = 0.0f;
    if (wx0 != 0.0f) {
      const float2 a00 = *(const float2*)(row0 + 2 * x0);
      ax = wx0 * a00.x; ay = wx0 * a00.y;
    }
    if (wx1 != 0.0f) {
      const float2 a01 = *(const float2*)(row0 + 2 * x1);
      ax += wx1 * a01.x; ay += wx1 * a01.y;
    }
    float ox = wy0 * ax, oy = wy0 * ay;

    if (need_y1) {
      float bx = 0.0f, by = 0.0f;
      if (wx0 != 0.0f) {
        const float2 a10 = *(const float2*)(row1 + 2 * x0);
        bx = wx0 * a10.x; by = wx0 * a10.y;
      }
      if (wx1 != 0.0f) {
        const float2 a11 = *(const float2*)(row1 + 2 * x1);
        bx += wx1 * a11.x; by += wx1 * a11.y;
      }
      ox += wy1 * bx; oy += wy1 * by;
    }
    vx[p] = ox; vy[p] = oy;
  }

  f32x4 r0, r1;
  r0.x = vx[0]; r0.y = vy[0]; r0.z = vx[1]; r0.w = vy[1];
  r1.x = vx[2]; r1.y = vy[2]; r1.z = vx[3]; r1.w = vy[3];

  f32x4* __restrict__ dst = (f32x4*)(out + off);
  __builtin_nontemporal_store(r0, dst);
  __builtin_nontemporal_store(r1, dst + 1);
}

extern "C" void kernel_launch(void* const* d_in, const int* in_sizes, int n_in,
                              void* d_out, int out_size, void* d_ws, size_t ws_size,
                              hipStream_t stream) {
  const float* in    = (const float*)d_in[0];
  const float* theta = (const float*)d_in[1];
  float* out = (float*)d_out;

  const int N = 32, H = 1024, W = 1024;
  // 4 pixels per thread, 256 threads/block -> 1024 px = one full row per block
  dim3 block(256, 1, 1);
  dim3 grid((W + 1023) / 1024, H, N);
  ComplexScaling_kernel<<<grid, block, 0, stream>>>(in, theta, out, H, W);
}

// Round 3
// 427.220 us; speedup vs baseline: 1.0721x; 1.0721x over previous
//
#include <hip/hip_runtime.h>

// ComplexScaling: separable bilinear resample, NHWC [N,H,W,2] fp32.
//
// Structural fact: for s == 1.0f and power-of-two H,W the coordinate chain
// ((s*((2j+1)/W - 1) + 1)*W - 1)/2 is EXACT in fp32 (all intermediates are
// dyadic rationals within 24-bit mantissa), so ix == j, iy == i and
// wx1 == wy1 == 0: the op is bitwise out = in. That case takes a dedicated
// copy path written in the m13 max-BW pattern: lane-contiguous float4
// (16 B lane stride -> 1 KB dense per wave instruction), plain loads/stores
// (NO nontemporal: nt bypasses L2 and amplified fetch traffic in R2),
// loads issued before stores for ILP.
//
// General bilinear path (arbitrary theta) retained below, 3D grid, no
// 64-bit integer divides.

typedef float f32x4 __attribute__((ext_vector_type(4)));

__global__ __launch_bounds__(256) void ComplexScaling_kernel(
    const float* __restrict__ in, const float* __restrict__ theta,
    float* __restrict__ out, int H, int W) {
  const float s = 1.0f + theta[0];

  const int i = blockIdx.y;                        // output row
  const int n = blockIdx.z;                        // batch
  const long long row_off = (long long)(n * H + i) * W * 2;  // floats

  // ---------- fast path: identity mapping -> pure row copy ----------
  // Grid-uniform branch (s is uniform across the grid), no divergence.
  if (s == 1.0f) {
    const f32x4* __restrict__ src = (const f32x4*)(in + row_off);
    f32x4* __restrict__ dst = (f32x4*)(out + row_off);
    const int nvec = W >> 1;                       // float4s per row (512)
    const int t = threadIdx.x;
    const int k1 = t + blockDim.x;
    // coalesced: lane stride 16 B; both loads in flight before stores
    f32x4 a = src[t];
    f32x4 b;
    bool has2 = (k1 < nvec);
    if (has2) b = src[k1];
    dst[t] = a;
    if (has2) dst[k1] = b;
    return;
  }

  // ---------- general path: separable bilinear gather ----------
  const int j = (blockIdx.x * blockDim.x + threadIdx.x) << 2;  // 4 px/thread
  if (j >= W) return;
  const long long off = row_off + (long long)j * 2;            // floats

  // row (y) coordinate: shared by all 4 pixels of this thread
  float yn  = (2.0f * (float)i + 1.0f) / (float)H - 1.0f;
  float iy  = ((s * yn + 1.0f) * (float)H - 1.0f) * 0.5f;
  float fy0 = floorf(iy);
  float wy1 = iy - fy0;
  float wy0 = 1.0f - wy1;
  float fy1 = fy0 + 1.0f;
  float Hm1 = (float)(H - 1);
  if (!(fy0 >= 0.0f && fy0 <= Hm1)) wy0 = 0.0f;   // zeros padding
  if (!(fy1 >= 0.0f && fy1 <= Hm1)) wy1 = 0.0f;
  int y0 = (int)fminf(fmaxf(fy0, 0.0f), Hm1);
  int y1 = (int)fminf(fmaxf(fy1, 0.0f), Hm1);

  const float* __restrict__ row0 = in + ((long long)(n * H + y0) * W) * 2;
  const float* __restrict__ row1 = in + ((long long)(n * H + y1) * W) * 2;
  const bool need_y1 = (wy1 != 0.0f);

  float Wm1 = (float)(W - 1);
  float vx[4], vy[4];

  #pragma unroll
  for (int p = 0; p < 4; ++p) {
    int jj = j + p;
    // column (x) coordinate
    float xn  = (2.0f * (float)jj + 1.0f) / (float)W - 1.0f;
    float ix  = ((s * xn + 1.0f) * (float)W - 1.0f) * 0.5f;
    float fx0 = floorf(ix);
    float wx1 = ix - fx0;
    float wx0 = 1.0f - wx1;
    float fx1 = fx0 + 1.0f;
    if (!(fx0 >= 0.0f && fx0 <= Wm1)) wx0 = 0.0f;  // zeros padding
    if (!(fx1 >= 0.0f && fx1 <= Wm1)) wx1 = 0.0f;
    int x0 = (int)fminf(fmaxf(fx0, 0.0f), Wm1);
    int x1 = (int)fminf(fmaxf(fx1, 0.0f), Wm1);

    float ax = 0.0f, ay = 0.0f;
    if (wx0 != 0.0f) {
      const float2 a00 = *(const float2*)(row0 + 2 * x0);
      ax = wx0 * a00.x; ay = wx0 * a00.y;
    }
    if (wx1 != 0.0f) {
      const float2 a01 = *(const float2*)(row0 + 2 * x1);
      ax += wx1 * a01.x; ay += wx1 * a01.y;
    }
    float ox = wy0 * ax, oy = wy0 * ay;

    if (need_y1) {
      float bx = 0.0f, by = 0.0f;
      if (wx0 != 0.0f) {
        const float2 a10 = *(const float2*)(row1 + 2 * x0);
        bx = wx0 * a10.x; by = wx0 * a10.y;
      }
      if (wx1 != 0.0f) {
        const float2 a11 = *(const float2*)(row1 + 2 * x1);
        bx += wx1 * a11.x; by += wx1 * a11.y;
      }
      ox += wy1 * bx; oy += wy1 * by;
    }
    vx[p] = ox; vy[p] = oy;
  }

  f32x4 r0, r1;
  r0.x = vx[0]; r0.y = vy[0]; r0.z = vx[1]; r0.w = vy[1];
  r1.x = vx[2]; r1.y = vy[2]; r1.z = vx[3]; r1.w = vy[3];

  f32x4* __restrict__ dst = (f32x4*)(out + off);
  dst[0] = r0;
  dst[1] = r1;
}

extern "C" void kernel_launch(void* const* d_in, const int* in_sizes, int n_in,
                              void* d_out, int out_size, void* d_ws, size_t ws_size,
                              hipStream_t stream) {
  const float* in    = (const float*)d_in[0];
  const float* theta = (const float*)d_in[1];
  float* out = (float*)d_out;

  const int N = 32, H = 1024, W = 1024;
  // one block per output row; 256 threads; fast path copies the row as
  // 512 float4s (2 per thread), general path does 4 px/thread.
  dim3 block(256, 1, 1);
  dim3 grid((W + 1023) / 1024, H, N);
  ComplexScaling_kernel<<<grid, block, 0, stream>>>(in, theta, out, H, W);
}